// Round 1
// 346.604 us; speedup vs baseline: 1.0180x; 1.0180x over previous
//
#include <hip/hip_runtime.h>
#include <stdint.h>

#define DIM    680
#define DPAD   768      // 3 x 256 tiles
#define NCH    864      // 55296 / 64 g-chunks
#define NB_Q   24
#define SPLITS 72
#define STAGES 12       // NCH / SPLITS
#define NTILE  6        // upper-triangle 256x256 tiles of 3x3
#define KSLICE 8        // k3 split-K factor (680 = 8 x 85)
#define KLEN   85

typedef __bf16 bf16x8 __attribute__((ext_vector_type(8)));
typedef float  f32x16 __attribute__((ext_vector_type(16)));

typedef __attribute__((address_space(3))) unsigned       lds_u32;
typedef __attribute__((address_space(1))) const unsigned glb_u32;

__constant__ int c_tj[NTILE] = {0, 0, 0, 1, 1, 2};
__constant__ int c_ti[NTILE] = {0, 1, 2, 1, 2, 2};

static __device__ __forceinline__ unsigned f2bf(float x) {
    union { float f; unsigned u; } c; c.f = x;
    unsigned u = c.u;
    return (u + 0x7FFFu + ((u >> 16) & 1u)) >> 16;  // RNE
}

static __device__ __forceinline__ float bf2f(unsigned short h) {
    union { unsigned u; float f; } c; c.u = ((unsigned)h) << 16;
    return c.f;
}

// ---------------------------------------------------------------------------
// k1-v2: D (55296 x 680 fp32) -> Awt bf16 (scaled by sqrt(qw[b])), chunk-
//     transposed for k2's DMA: 16B slot (cg, col i, kc) at uint4 index
//     ((cg*768 + i)*8 + (kc ^ (i&7))) holding g = cg*64 + kc*8 + 0..7 of col i.
//     Staging: global_load_lds width=16 of RAW fp32 (no VGPR round-trip).
//     Lane->colgroup XOR swizzle (sg = (t&15) ^ (row>>3)) makes the forced
//     lane-contiguous LDS layout 2-way-conflict-only for column gathers.
//     Cols >= 680 are pre-zeroed once (mask depends only on (t, rd)).
// ---------------------------------------------------------------------------
__global__ __launch_bounds__(256) void k1_transpose(
        const float* __restrict__ D, const float* __restrict__ qw,
        uint4* __restrict__ awt) {
    __shared__ float sq[NB_Q];
    __shared__ float tile[4096];   // 64 rows x 64 cols fp32, swizzled colgroups
    const int t   = threadIdx.x;
    const int cg0 = blockIdx.x * 4;
    const int i0  = blockIdx.y * 64;
    if (t < NB_Q) sq[t] = sqrtf(qw[t]);

    int  rowr[4], gcol[4];
    bool inb[4];
#pragma unroll
    for (int rd = 0; rd < 4; ++rd) {
        const int row = rd * 16 + (t >> 4);
        const int p   = row >> 3;
        const int sg  = (t & 15) ^ p;
        rowr[rd] = row;
        gcol[rd] = i0 + sg * 4;          // multiple of 4; 680%4==0 -> no straddle
        inb[rd]  = (gcol[rd] < DIM);
        if (!inb[rd]) {                  // zero once; OOB slots stay zero
            float4 z = {0.f, 0.f, 0.f, 0.f};
            *reinterpret_cast<float4*>(&tile[rd * 1024 + t * 4]) = z;
        }
    }
    __syncthreads();   // sq + zeros visible

    for (int cc = 0; cc < 4; ++cc) {
        const int cg = cg0 + cc;
        const int g0 = cg * 64;
#pragma unroll
        for (int rd = 0; rd < 4; ++rd) {
            if (inb[rd]) {
                __builtin_amdgcn_global_load_lds(
                    (glb_u32*)(D + (size_t)(g0 + rowr[rd]) * DIM + gcol[rd]),
                    (lds_u32*)(&tile[rd * 1024 + t * 4]), 16, 0, 0);
            }
        }
        __syncthreads();   // drains DMA

#pragma unroll
        for (int s = 0; s < 2; ++s) {
            const int l  = t + s * 256;
            const int c  = l >> 3;       // local col 0..63
            const int kc = l & 7;        // 16B chunk within col
            unsigned h[8];
#pragma unroll
            for (int j = 0; j < 8; ++j) {
                const int row = kc * 8 + j;
                const float v = tile[row * 64 + (((c >> 2) ^ kc) << 2) + (c & 3)];
                const int b = ((g0 + row) / 48) % 24;
                h[j] = f2bf(v * sq[b]);
            }
            uint4 o;
            o.x = h[0] | (h[1] << 16);
            o.y = h[2] | (h[3] << 16);
            o.z = h[4] | (h[5] << 16);
            o.w = h[6] | (h[7] << 16);
            const size_t slot = ((size_t)cg * DPAD + (size_t)(i0 + c)) * 8
                              + (size_t)(kc ^ (c & 7));
            awt[slot] = o;
        }
        __syncthreads();   // protect tile before next chunk's DMA
    }
}

// ---------------------------------------------------------------------------
// k2-v3: partial[split][tile] = sum over this split's 12 chunks of
//     A_band(tj)^T * A_band(ti), upper-triangle tiles only (M symmetric).
//     grid (72 splits, 6 tiles), 512 threads = 8 waves (4 m x 2 n),
//     wave tile 64x128, mfma_f32_32x32x16_bf16.
//     v3 changes vs v2:
//       (a) double-buffered LDS (128 KB) + prefetch-before-compute (T3
//           2-phase): VGPRs (~170, acc alone 128) cap occupancy at 1
//           block/CU, so the old STAGE->drain->compute structure had NO
//           wave overlap of DMA with MFMA; the prefetch hides next-stage
//           load latency/BW under current-stage MFMA. LDS was free (64->128
//           of 160 KB) since occupancy is VGPR-bound anyway.
//       (b) diagonal tiles (tj==ti) load one band and alias pB = pA:
//           awt band re-reads 12 -> 9 (-83 MB HBM / L2 traffic).
// ---------------------------------------------------------------------------
__global__ __launch_bounds__(512) void k2_gram(const uint4* __restrict__ awt,
                                               uint2* __restrict__ parts) {
    __shared__ uint4 smA[2][2048];   // 256 cols x 8 slots (swizzled), 2x32 KB
    __shared__ uint4 smB[2][2048];
    const int t     = threadIdx.x;
    const int split = blockIdx.x;
    const int t6    = blockIdx.y;
    const int tj    = c_tj[t6];   // row band of M
    const int ti    = c_ti[t6];   // col band of M
    const bool diag = (tj == ti);
    const int wave  = t >> 6;
    const int lane  = t & 63;
    const int wm    = wave & 3;   // m: 64-row band
    const int wn    = wave >> 2;  // n: 128-col band
    const int cl    = lane & 31;
    const int half  = lane >> 5;

    f32x16 acc[2][4];
    const f32x16 zero = {};
#pragma unroll
    for (int a = 0; a < 2; ++a)
#pragma unroll
        for (int b = 0; b < 4; ++b) acc[a][b] = zero;

    // STAGE(st, buf): issue async global->LDS copies for chunk st into buf.
    // Linear copy: slot layout in LDS == slot layout in awt band (swizzle
    // was baked in by k1), dest is wave-uniform base + lane*16 as required.
#define K2_STAGE(st_, buf_)                                                   \
    do {                                                                      \
        const int    cg_ = split * STAGES + (st_);                            \
        const size_t bA_ = ((size_t)cg_ * DPAD + tj * 256) * 8;               \
        _Pragma("unroll")                                                     \
        for (int j = 0; j < 4; ++j) {                                         \
            __builtin_amdgcn_global_load_lds(                                 \
                (glb_u32*)(awt + bA_ + j * 512 + t),                          \
                (lds_u32*)(&smA[(buf_)][j * 512 + t]), 16, 0, 0);             \
        }                                                                     \
        if (!diag) {                                                          \
            const size_t bB_ = ((size_t)cg_ * DPAD + ti * 256) * 8;           \
            _Pragma("unroll")                                                 \
            for (int j = 0; j < 4; ++j) {                                     \
                __builtin_amdgcn_global_load_lds(                             \
                    (glb_u32*)(awt + bB_ + j * 512 + t),                      \
                    (lds_u32*)(&smB[(buf_)][j * 512 + t]), 16, 0, 0);         \
            }                                                                 \
        }                                                                     \
    } while (0)

    K2_STAGE(0, 0);
    __syncthreads();   // drain prologue DMA (vmcnt(0) inside syncthreads)

    for (int st = 0; st < STAGES; ++st) {
        const int cur = st & 1;
        // Prefetch next chunk into the other buffer; it flies during the
        // MFMA phase below and is drained by the end-of-iteration barrier.
        // buf cur^1 was last READ in iteration st-1 (barrier-protected).
        if (st + 1 < STAGES) K2_STAGE(st + 1, cur ^ 1);

        const bf16x8* pA = reinterpret_cast<const bf16x8*>(smA[cur]);
        const bf16x8* pB = diag ? pA : reinterpret_cast<const bf16x8*>(smB[cur]);
#pragma unroll
        for (int t4 = 0; t4 < 4; ++t4) {          // K = 64 per stage, 16/mfma
            const int kc = 2 * t4 + half;
            bf16x8 af[2], bfr[4];
#pragma unroll
            for (int ms = 0; ms < 2; ++ms) {
                const int col = wm * 64 + ms * 32 + cl;
                af[ms] = pA[col * 8 + (kc ^ (col & 7))];
            }
#pragma unroll
            for (int ns = 0; ns < 4; ++ns) {
                const int col = wn * 128 + ns * 32 + cl;
                bfr[ns] = pB[col * 8 + (kc ^ (col & 7))];
            }
#pragma unroll
            for (int ms = 0; ms < 2; ++ms)
#pragma unroll
                for (int ns = 0; ns < 4; ++ns)
                    acc[ms][ns] = __builtin_amdgcn_mfma_f32_32x32x16_bf16(
                        af[ms], bfr[ns], acc[ms][ns], 0, 0, 0);
        }
        __syncthreads();   // drains prefetch DMA + protects cur for reuse
    }
#undef K2_STAGE

    // row-quad packed bf16 stores: full-line coalesced, no atomics
    uint2* pt = parts + (size_t)(split * NTILE + t6) * 16384;
#pragma unroll
    for (int ms = 0; ms < 2; ++ms) {
        const int rowb = wm * 64 + ms * 32 + 4 * half;   // multiple of 4
#pragma unroll
        for (int ns = 0; ns < 4; ++ns) {
            const int colt = wn * 128 + ns * 32 + cl;
#pragma unroll
            for (int q = 0; q < 4; ++q) {                // rows rowb+8q .. +3
                uint2 w;
                w.x = f2bf(acc[ms][ns][q * 4 + 0]) | (f2bf(acc[ms][ns][q * 4 + 1]) << 16);
                w.y = f2bf(acc[ms][ns][q * 4 + 2]) | (f2bf(acc[ms][ns][q * 4 + 3]) << 16);
                pt[(size_t)(((rowb >> 2) + 2 * q) * 256 + colt)] = w;
            }
        }
    }
}

// ---------------------------------------------------------------------------
// k2r: M[768x768 fp32] = sum over 72 split-partials per tile, + mirror.
//     Tile layout: u64 word w = quad*256 + col -> rows 4*quad..+3 of col.
//     grid (32, 6), 256 threads, uint4 (2 words = 2 cols x 4 rows) per thread.
// ---------------------------------------------------------------------------
__global__ __launch_bounds__(256) void k2_reduce(
        const uint2* __restrict__ parts, float* __restrict__ M) {
    const int t6 = blockIdx.y;
    const int tj = c_tj[t6];
    const int ti = c_ti[t6];
    const int idx4 = blockIdx.x * 256 + threadIdx.x;   // uint4 index, 8192/tile
    const int w0 = idx4 * 2;
    const int quad = w0 >> 8;
    const int c = w0 & 255;                            // even
    float s[8] = {0.f, 0.f, 0.f, 0.f, 0.f, 0.f, 0.f, 0.f};
    const uint4* base = reinterpret_cast<const uint4*>(parts) + idx4;
#pragma unroll 8
    for (int sp = 0; sp < SPLITS; ++sp) {
        const uint4 u = base[(size_t)(sp * NTILE + t6) * 8192];
        s[0] += bf2f((unsigned short)(u.x & 0xFFFF));
        s[1] += bf2f((unsigned short)(u.x >> 16));
        s[2] += bf2f((unsigned short)(u.y & 0xFFFF));
        s[3] += bf2f((unsigned short)(u.y >> 16));
        s[4] += bf2f((unsigned short)(u.z & 0xFFFF));
        s[5] += bf2f((unsigned short)(u.z >> 16));
        s[6] += bf2f((unsigned short)(u.w & 0xFFFF));
        s[7] += bf2f((unsigned short)(u.w >> 16));
    }
    const int R = tj * 256 + 4 * quad;
    const int C = ti * 256 + c;
#pragma unroll
    for (int i = 0; i < 4; ++i) {
        float2 d = {s[i], s[4 + i]};
        *reinterpret_cast<float2*>(M + (size_t)(R + i) * DPAD + C) = d;
    }
    if (ti != tj) {
        float4 m0 = {s[0], s[1], s[2], s[3]};
        float4 m1 = {s[4], s[5], s[6], s[7]};
        *reinterpret_cast<float4*>(M + (size_t)(C + 0) * DPAD + R) = m0;
        *reinterpret_cast<float4*>(M + (size_t)(C + 1) * DPAD + R) = m1;
    }
}

// ---------------------------------------------------------------------------
// k3: outp[ks](1024x680) = F(:, ks-slice) @ M(ks-slice, :), split-K over 8
//     slices of 85. fp32 tiled GEMM, 64x64 tile, 256 threads, 4x4/thread.
//     grid (16, 11, 8) = 1408 blocks.
// ---------------------------------------------------------------------------
__global__ __launch_bounds__(256) void k3_out(const float* __restrict__ F,
                                              const float* __restrict__ M,
                                              float* __restrict__ outp) {
    __shared__ float Ft[32][68];   // [k][n]
    __shared__ float Ms[32][68];   // [k][i]
    const int t  = threadIdx.x;
    const int tx = t & 15;
    const int ty = t >> 4;
    const int n0 = blockIdx.x * 64;
    const int i0 = blockIdx.y * 64;
    const int ks = blockIdx.z;
    const int kbeg = ks * KLEN;
    const int kend = kbeg + KLEN;
    float acc[4][4] = {};

    for (int k0 = kbeg; k0 < kend; k0 += 32) {
        __syncthreads();
        {
            const int kk = t & 31;
            const int nb = t >> 5;
            const int k = k0 + kk;
#pragma unroll
            for (int rr = 0; rr < 8; ++rr) {
                const int n = nb * 8 + rr;
                Ft[kk][n] = (k < kend) ? F[(size_t)(n0 + n) * DIM + k] : 0.f;
            }
        }
        {
            const int i  = t & 63;
            const int kb = t >> 6;
#pragma unroll
            for (int rr = 0; rr < 8; ++rr) {
                const int kk = kb * 8 + rr;
                const int k = k0 + kk;
                Ms[kk][i] = (k < kend) ? M[(size_t)k * DPAD + i0 + i] : 0.f;
            }
        }
        __syncthreads();
#pragma unroll
        for (int kk = 0; kk < 32; ++kk) {
            const float4 a = *reinterpret_cast<const float4*>(&Ft[kk][ty * 4]);
            const float4 b = *reinterpret_cast<const float4*>(&Ms[kk][tx * 4]);
            acc[0][0] += a.x * b.x; acc[0][1] += a.x * b.y;
            acc[0][2] += a.x * b.z; acc[0][3] += a.x * b.w;
            acc[1][0] += a.y * b.x; acc[1][1] += a.y * b.y;
            acc[1][2] += a.y * b.z; acc[1][3] += a.y * b.w;
            acc[2][0] += a.z * b.x; acc[2][1] += a.z * b.y;
            acc[2][2] += a.z * b.z; acc[2][3] += a.z * b.w;
            acc[3][0] += a.w * b.x; acc[3][1] += a.w * b.y;
            acc[3][2] += a.w * b.z; acc[3][3] += a.w * b.w;
        }
    }

    float* op = outp + (size_t)ks * ((size_t)1024 * DIM);
#pragma unroll
    for (int r = 0; r < 4; ++r) {
        const int n = n0 + ty * 4 + r;
#pragma unroll
        for (int c = 0; c < 4; ++c) {
            const int i = i0 + tx * 4 + c;
            if (i < DIM) op[(size_t)n * DIM + i] = acc[r][c];
        }
    }
}

// ---------------------------------------------------------------------------
// k3r: out = sum of 8 K-slice partials. 680 blocks x 256 threads x float4.
// ---------------------------------------------------------------------------
__global__ __launch_bounds__(256) void k3_reduce(
        const float4* __restrict__ outp, float4* __restrict__ out) {
    const int idx = blockIdx.x * 256 + threadIdx.x;   // 174080 float4's
    const int N4 = 1024 * DIM / 4;
    float4 s = {0.f, 0.f, 0.f, 0.f};
#pragma unroll
    for (int p = 0; p < KSLICE; ++p) {
        const float4 a = outp[(size_t)p * N4 + idx];
        s.x += a.x; s.y += a.y; s.z += a.z; s.w += a.w;
    }
    out[idx] = s;
}

extern "C" void kernel_launch(void* const* d_in, const int* in_sizes, int n_in,
                              void* d_out, int out_size, void* d_ws, size_t ws_size,
                              hipStream_t stream) {
    const float* F  = (const float*)d_in[0];   // (1024, 680)
    const float* D  = (const float*)d_in[1];   // (48, 24, 48, 680)
    const float* qw = (const float*)d_in[2];   // (24,)
    float* out = (float*)d_out;
    char*  ws  = (char*)d_ws;

    uint4* awt = (uint4*)ws;                                    // 81.0 MiB bf16
    const size_t awt_bytes = (size_t)NCH * DPAD * 64 * 2;       // 84,934,656
    uint2* parts = (uint2*)(ws + awt_bytes);                    // 54.0 MiB bf16
    const size_t parts_bytes = (size_t)SPLITS * NTILE * 65536 * 2;  // 56,623,104
    float* M = (float*)(ws + awt_bytes + parts_bytes);          // 2.25 MiB fp32
    // k3 partials alias awt (dead after k2_gram; stream-ordered): 22.3 MiB
    float* outp = (float*)ws;

    k1_transpose<<<dim3(NCH / 4, DPAD / 64), 256, 0, stream>>>(D, qw, awt);
    k2_gram<<<dim3(SPLITS, NTILE), 512, 0, stream>>>(awt, parts);
    k2_reduce<<<dim3(32, NTILE), 256, 0, stream>>>(parts, M);
    k3_out<<<dim3(16, 11, KSLICE), 256, 0, stream>>>(F, M, outp);
    k3_reduce<<<dim3(1024 * DIM / 4 / 256), 256, 0, stream>>>(
        (const float4*)outp, (float4*)out);
}

// Round 2
// 303.455 us; speedup vs baseline: 1.1627x; 1.1422x over previous
//
#include <hip/hip_runtime.h>
#include <stdint.h>

#define DIM    680
#define DPAD   768      // 3 x 256 tiles
#define NCH    864      // 55296 / 64 g-chunks
#define NB_Q   24
#define SPLITS 36
#define STAGES 24       // NCH / SPLITS
#define NTILE  6        // upper-triangle 256x256 tiles of 3x3

typedef __bf16 bf16x8 __attribute__((ext_vector_type(8)));
typedef float  f32x16 __attribute__((ext_vector_type(16)));

typedef __attribute__((address_space(3))) unsigned       lds_u32;
typedef __attribute__((address_space(1))) const unsigned glb_u32;

__constant__ int c_tj[NTILE] = {0, 0, 0, 1, 1, 2};
__constant__ int c_ti[NTILE] = {0, 1, 2, 1, 2, 2};

static __device__ __forceinline__ unsigned f2bf(float x) {
    union { float f; unsigned u; } c; c.f = x;
    unsigned u = c.u;
    return (u + 0x7FFFu + ((u >> 16) & 1u)) >> 16;  // RNE
}

static __device__ __forceinline__ float bf2f(unsigned short h) {
    union { unsigned u; float f; } c; c.u = ((unsigned)h) << 16;
    return c.f;
}

// ---------------------------------------------------------------------------
// k1-v2: D (55296 x 680 fp32) -> Awt bf16 (scaled by sqrt(qw[b])), chunk-
//     transposed for k2's DMA: 16B slot (cg, col i, kc) at uint4 index
//     ((cg*768 + i)*8 + (kc ^ (i&7))) holding g = cg*64 + kc*8 + 0..7 of col i.
//     Staging: global_load_lds width=16 of RAW fp32 (no VGPR round-trip).
//     Lane->colgroup XOR swizzle (sg = (t&15) ^ (row>>3)) makes the forced
//     lane-contiguous LDS layout 2-way-conflict-only for column gathers.
//     Cols >= 680 are pre-zeroed once (mask depends only on (t, rd)).
// ---------------------------------------------------------------------------
__global__ __launch_bounds__(256) void k1_transpose(
        const float* __restrict__ D, const float* __restrict__ qw,
        uint4* __restrict__ awt) {
    __shared__ float sq[NB_Q];
    __shared__ float tile[4096];   // 64 rows x 64 cols fp32, swizzled colgroups
    const int t   = threadIdx.x;
    const int cg0 = blockIdx.x * 4;
    const int i0  = blockIdx.y * 64;
    if (t < NB_Q) sq[t] = sqrtf(qw[t]);

    int  rowr[4], gcol[4];
    bool inb[4];
#pragma unroll
    for (int rd = 0; rd < 4; ++rd) {
        const int row = rd * 16 + (t >> 4);
        const int p   = row >> 3;
        const int sg  = (t & 15) ^ p;
        rowr[rd] = row;
        gcol[rd] = i0 + sg * 4;          // multiple of 4; 680%4==0 -> no straddle
        inb[rd]  = (gcol[rd] < DIM);
        if (!inb[rd]) {                  // zero once; OOB slots stay zero
            float4 z = {0.f, 0.f, 0.f, 0.f};
            *reinterpret_cast<float4*>(&tile[rd * 1024 + t * 4]) = z;
        }
    }
    __syncthreads();   // sq + zeros visible

    for (int cc = 0; cc < 4; ++cc) {
        const int cg = cg0 + cc;
        const int g0 = cg * 64;
#pragma unroll
        for (int rd = 0; rd < 4; ++rd) {
            if (inb[rd]) {
                __builtin_amdgcn_global_load_lds(
                    (glb_u32*)(D + (size_t)(g0 + rowr[rd]) * DIM + gcol[rd]),
                    (lds_u32*)(&tile[rd * 1024 + t * 4]), 16, 0, 0);
            }
        }
        __syncthreads();   // drains DMA

#pragma unroll
        for (int s = 0; s < 2; ++s) {
            const int l  = t + s * 256;
            const int c  = l >> 3;       // local col 0..63
            const int kc = l & 7;        // 16B chunk within col
            unsigned h[8];
#pragma unroll
            for (int j = 0; j < 8; ++j) {
                const int row = kc * 8 + j;
                const float v = tile[row * 64 + (((c >> 2) ^ kc) << 2) + (c & 3)];
                const int b = ((g0 + row) / 48) % 24;
                h[j] = f2bf(v * sq[b]);
            }
            uint4 o;
            o.x = h[0] | (h[1] << 16);
            o.y = h[2] | (h[3] << 16);
            o.z = h[4] | (h[5] << 16);
            o.w = h[6] | (h[7] << 16);
            const size_t slot = ((size_t)cg * DPAD + (size_t)(i0 + c)) * 8
                              + (size_t)(kc ^ (c & 7));
            awt[slot] = o;
        }
        __syncthreads();   // protect tile before next chunk's DMA
    }
}

// ---------------------------------------------------------------------------
// kF: F (1024 x 680 fp32) -> Fb bf16 (1024 x 768, k-padded with zeros),
//     row-major. 768%8==0 and 680%8==0 -> clean uint4 (8 bf16) packing.
// ---------------------------------------------------------------------------
__global__ __launch_bounds__(256) void kf_conv(const float* __restrict__ F,
                                               uint4* __restrict__ Fb) {
    const int idx = blockIdx.x * 256 + threadIdx.x;   // 98304 uint4's
    const int row = idx / 96;                         // 768/8 = 96 per row
    const int c0  = (idx % 96) * 8;
    uint4 o = {0u, 0u, 0u, 0u};
    if (c0 < DIM) {
        const float4 a = *reinterpret_cast<const float4*>(F + (size_t)row * DIM + c0);
        const float4 b = *reinterpret_cast<const float4*>(F + (size_t)row * DIM + c0 + 4);
        o.x = f2bf(a.x) | (f2bf(a.y) << 16);
        o.y = f2bf(a.z) | (f2bf(a.w) << 16);
        o.z = f2bf(b.x) | (f2bf(b.y) << 16);
        o.w = f2bf(b.z) | (f2bf(b.w) << 16);
    }
    Fb[idx] = o;
}

// ---------------------------------------------------------------------------
// k2-v4: partial[split][tile] = sum over this split's 24 chunks of
//     A_band(tj)^T * A_band(ti), upper-triangle tiles only (M symmetric).
//     216 blocks (36 splits x 6 tiles), 512 threads = 8 waves (4m x 2n),
//     wave tile 64x128, mfma_f32_32x32x16_bf16, double-buffered 2-phase.
//     v4 changes vs v3:
//       (a) SPLITS 72 -> 36: identical makespan (216 blocks @ 1 round / 84%
//           == 432 @ 2 rounds / 84%) but parts traffic halves (-56 MB over
//           k2+k2r) -- k2 is traffic-bound, prefetch alone gave only -6us.
//       (b) XCD-chunked swizzle (216 = 8 XCDs x 27): the 6 tile-blocks of a
//           split become co-resident on ONE XCD, so each chunk's 3 bands
//           are fetched into that L2 once and served for all 9 band-reads
//           (read amplification 3x -> ~1x at the L2 boundary).
// ---------------------------------------------------------------------------
__global__ __launch_bounds__(512) void k2_gram(const uint4* __restrict__ awt,
                                               uint2* __restrict__ parts) {
    __shared__ uint4 smA[2][2048];   // 256 cols x 8 slots (swizzled), 2x32 KB
    __shared__ uint4 smB[2][2048];
    const int t  = threadIdx.x;
    // HW round-robins linear block id over 8 XCDs; remap so each XCD gets a
    // contiguous run of 27 logical ids -> same-split tiles share an L2.
    const int h       = blockIdx.x;              // 0..215
    const int logical = (h & 7) * 27 + (h >> 3); // bijective (216 = 8*27)
    const int split   = logical / 6;
    const int t6      = logical % 6;
    const int tj    = c_tj[t6];   // row band of M
    const int ti    = c_ti[t6];   // col band of M
    const bool diag = (tj == ti);
    const int wave  = t >> 6;
    const int lane  = t & 63;
    const int wm    = wave & 3;   // m: 64-row band
    const int wn    = wave >> 2;  // n: 128-col band
    const int cl    = lane & 31;
    const int half  = lane >> 5;

    f32x16 acc[2][4];
    const f32x16 zero = {};
#pragma unroll
    for (int a = 0; a < 2; ++a)
#pragma unroll
        for (int b = 0; b < 4; ++b) acc[a][b] = zero;

#define K2_STAGE(st_, buf_)                                                   \
    do {                                                                      \
        const int    cg_ = split * STAGES + (st_);                            \
        const size_t bA_ = ((size_t)cg_ * DPAD + tj * 256) * 8;               \
        _Pragma("unroll")                                                     \
        for (int j = 0; j < 4; ++j) {                                         \
            __builtin_amdgcn_global_load_lds(                                 \
                (glb_u32*)(awt + bA_ + j * 512 + t),                          \
                (lds_u32*)(&smA[(buf_)][j * 512 + t]), 16, 0, 0);             \
        }                                                                     \
        if (!diag) {                                                          \
            const size_t bB_ = ((size_t)cg_ * DPAD + ti * 256) * 8;           \
            _Pragma("unroll")                                                 \
            for (int j = 0; j < 4; ++j) {                                     \
                __builtin_amdgcn_global_load_lds(                             \
                    (glb_u32*)(awt + bB_ + j * 512 + t),                      \
                    (lds_u32*)(&smB[(buf_)][j * 512 + t]), 16, 0, 0);         \
            }                                                                 \
        }                                                                     \
    } while (0)

    K2_STAGE(0, 0);
    __syncthreads();   // drain prologue DMA

    for (int st = 0; st < STAGES; ++st) {
        const int cur = st & 1;
        if (st + 1 < STAGES) K2_STAGE(st + 1, cur ^ 1);

        const bf16x8* pA = reinterpret_cast<const bf16x8*>(smA[cur]);
        const bf16x8* pB = diag ? pA : reinterpret_cast<const bf16x8*>(smB[cur]);
#pragma unroll
        for (int t4 = 0; t4 < 4; ++t4) {          // K = 64 per stage, 16/mfma
            const int kc = 2 * t4 + half;
            bf16x8 af[2], bfr[4];
#pragma unroll
            for (int ms = 0; ms < 2; ++ms) {
                const int col = wm * 64 + ms * 32 + cl;
                af[ms] = pA[col * 8 + (kc ^ (col & 7))];
            }
#pragma unroll
            for (int ns = 0; ns < 4; ++ns) {
                const int col = wn * 128 + ns * 32 + cl;
                bfr[ns] = pB[col * 8 + (kc ^ (col & 7))];
            }
#pragma unroll
            for (int ms = 0; ms < 2; ++ms)
#pragma unroll
                for (int ns = 0; ns < 4; ++ns)
                    acc[ms][ns] = __builtin_amdgcn_mfma_f32_32x32x16_bf16(
                        af[ms], bfr[ns], acc[ms][ns], 0, 0, 0);
        }
        __syncthreads();   // drains prefetch DMA + protects cur for reuse
    }
#undef K2_STAGE

    // row-quad packed bf16 stores: full-line coalesced, no atomics
    uint2* pt = parts + (size_t)(split * NTILE + t6) * 16384;
#pragma unroll
    for (int ms = 0; ms < 2; ++ms) {
        const int rowb = wm * 64 + ms * 32 + 4 * half;   // multiple of 4
#pragma unroll
        for (int ns = 0; ns < 4; ++ns) {
            const int colt = wn * 128 + ns * 32 + cl;
#pragma unroll
            for (int q = 0; q < 4; ++q) {                // rows rowb+8q .. +3
                uint2 w;
                w.x = f2bf(acc[ms][ns][q * 4 + 0]) | (f2bf(acc[ms][ns][q * 4 + 1]) << 16);
                w.y = f2bf(acc[ms][ns][q * 4 + 2]) | (f2bf(acc[ms][ns][q * 4 + 3]) << 16);
                pt[(size_t)(((rowb >> 2) + 2 * q) * 256 + colt)] = w;
            }
        }
    }
}

// ---------------------------------------------------------------------------
// k2r-v2: Mb[768x768 bf16] = sum over 36 split-partials per tile, + mirror.
//     Writes bf16 directly in k3's operand format (M is symmetric, so
//     row-major Mb serves as both M and M^T). No fp32 M anymore.
// ---------------------------------------------------------------------------
__global__ __launch_bounds__(256) void k2_reduce(
        const uint2* __restrict__ parts, unsigned short* __restrict__ Mb) {
    const int t6 = blockIdx.y;
    const int tj = c_tj[t6];
    const int ti = c_ti[t6];
    const int idx4 = blockIdx.x * 256 + threadIdx.x;   // uint4 index, 8192/tile
    const int w0 = idx4 * 2;
    const int quad = w0 >> 8;
    const int c = w0 & 255;                            // even
    float s[8] = {0.f, 0.f, 0.f, 0.f, 0.f, 0.f, 0.f, 0.f};
    const uint4* base = reinterpret_cast<const uint4*>(parts) + idx4;
#pragma unroll 4
    for (int sp = 0; sp < SPLITS; ++sp) {
        const uint4 u = base[(size_t)(sp * NTILE + t6) * 8192];
        s[0] += bf2f((unsigned short)(u.x & 0xFFFF));
        s[1] += bf2f((unsigned short)(u.x >> 16));
        s[2] += bf2f((unsigned short)(u.y & 0xFFFF));
        s[3] += bf2f((unsigned short)(u.y >> 16));
        s[4] += bf2f((unsigned short)(u.z & 0xFFFF));
        s[5] += bf2f((unsigned short)(u.z >> 16));
        s[6] += bf2f((unsigned short)(u.w & 0xFFFF));
        s[7] += bf2f((unsigned short)(u.w >> 16));
    }
    const int R = tj * 256 + 4 * quad;
    const int C = ti * 256 + c;
#pragma unroll
    for (int i = 0; i < 4; ++i) {      // rows R..R+3, cols C,C+1
        const unsigned w = f2bf(s[i]) | (f2bf(s[4 + i]) << 16);
        *reinterpret_cast<unsigned*>(Mb + (size_t)(R + i) * DPAD + C) = w;
    }
    if (ti != tj) {                    // mirror: rows C,C+1, cols R..R+3
        uint2 m0, m1;
        m0.x = f2bf(s[0]) | (f2bf(s[1]) << 16);
        m0.y = f2bf(s[2]) | (f2bf(s[3]) << 16);
        m1.x = f2bf(s[4]) | (f2bf(s[5]) << 16);
        m1.y = f2bf(s[6]) | (f2bf(s[7]) << 16);
        *reinterpret_cast<uint2*>(Mb + (size_t)(C + 0) * DPAD + R) = m0;
        *reinterpret_cast<uint2*>(Mb + (size_t)(C + 1) * DPAD + R) = m1;
    }
}

// ---------------------------------------------------------------------------
// k3-v2: out(1024 x 680) = F @ M via bf16 MFMA, full K=768 (no split-K, no
//     reduce kernel, no fp32 partial round-trip). Operands Fb/Mb are bf16
//     row-major with rows = contiguous K runs (M symmetric -> rows==cols).
//     1 wave / block, 64x64 output tile, grid (16, 11) = 176 blocks; both
//     operands (~2.7 MB) are L2-resident. Staging: global_load_lds with
//     source-side XOR pre-swizzle (LDS dest is forced lane-linear),
//     double-buffered with counted vmcnt(16) (single-wave => explicit
//     waitcnt instead of __syncthreads, which could be elided).
// ---------------------------------------------------------------------------
__global__ __launch_bounds__(64) void k3_mfma(const uint4* __restrict__ Fb,
                                              const uint4* __restrict__ Mb,
                                              float* __restrict__ out) {
    __shared__ uint4 sA[2][512];   // 64 cols x 8 k-chunks, swizzled, 2x8 KB
    __shared__ uint4 sB[2][512];
    const int t    = threadIdx.x;   // 0..63
    const int n0   = blockIdx.x * 64;
    const int i0   = blockIdx.y * 64;
    const int cl   = t & 31;
    const int half = t >> 5;

    f32x16 acc[2][2];
    const f32x16 zero = {};
    acc[0][0] = zero; acc[0][1] = zero; acc[1][0] = zero; acc[1][1] = zero;

    // load j, lane t -> LDS slot j*64+t == (n_loc, kcs) with n_loc=j*8+(t>>3),
    // kcs=t&7; source chunk pre-swizzled so slot (col, kc^(col&7)) holds kc.
#define K3_STAGE(ck_, buf_)                                                   \
    do {                                                                      \
        const int kcs_ = t & 7;                                               \
        _Pragma("unroll")                                                     \
        for (int j = 0; j < 8; ++j) {                                         \
            const int nl_ = j * 8 + (t >> 3);                                 \
            const int sc_ = (ck_) * 8 + (kcs_ ^ (nl_ & 7));                   \
            __builtin_amdgcn_global_load_lds(                                 \
                (glb_u32*)(Fb + (size_t)(n0 + nl_) * 96 + sc_),               \
                (lds_u32*)(&sA[(buf_)][j * 64 + t]), 16, 0, 0);               \
            __builtin_amdgcn_global_load_lds(                                 \
                (glb_u32*)(Mb + (size_t)(i0 + nl_) * 96 + sc_),               \
                (lds_u32*)(&sB[(buf_)][j * 64 + t]), 16, 0, 0);               \
        }                                                                     \
    } while (0)

    K3_STAGE(0, 0);
    asm volatile("s_waitcnt vmcnt(0)" ::: "memory");

    for (int ck = 0; ck < 12; ++ck) {          // K = 768 = 12 x 64
        const int cur = ck & 1;
        if (ck + 1 < 12) {
            // prior ds_reads of buf cur^1 completed (consumed by ck-1 MFMAs)
            asm volatile("s_waitcnt lgkmcnt(0)" ::: "memory");
            K3_STAGE(ck + 1, cur ^ 1);
            asm volatile("s_waitcnt vmcnt(16)" ::: "memory");  // cur's 16 done
        }
        const bf16x8* pA = reinterpret_cast<const bf16x8*>(sA[cur]);
        const bf16x8* pB = reinterpret_cast<const bf16x8*>(sB[cur]);
#pragma unroll
        for (int t4 = 0; t4 < 4; ++t4) {
            const int kc = 2 * t4 + half;
            bf16x8 af[2], bv[2];
#pragma unroll
            for (int ms = 0; ms < 2; ++ms) {
                const int col = ms * 32 + cl;
                af[ms] = pA[col * 8 + (kc ^ (col & 7))];
            }
#pragma unroll
            for (int ns = 0; ns < 2; ++ns) {
                const int col = ns * 32 + cl;
                bv[ns] = pB[col * 8 + (kc ^ (col & 7))];
            }
#pragma unroll
            for (int ms = 0; ms < 2; ++ms)
#pragma unroll
                for (int ns = 0; ns < 2; ++ns)
                    acc[ms][ns] = __builtin_amdgcn_mfma_f32_32x32x16_bf16(
                        af[ms], bv[ns], acc[ms][ns], 0, 0, 0);
        }
    }
#undef K3_STAGE

    // C layout (32x32): col = lane&31, row = (reg&3) + 8*(reg>>2) + 4*half
#pragma unroll
    for (int ms = 0; ms < 2; ++ms) {
        const int rowb = ms * 32 + 4 * half;
#pragma unroll
        for (int ns = 0; ns < 2; ++ns) {
            const int col = i0 + ns * 32 + cl;
            if (col < DIM) {
#pragma unroll
                for (int q = 0; q < 4; ++q)
#pragma unroll
                    for (int j = 0; j < 4; ++j)
                        out[(size_t)(n0 + rowb + 8 * q + j) * DIM + col]
                            = acc[ms][ns][4 * q + j];
            }
        }
    }
}

extern "C" void kernel_launch(void* const* d_in, const int* in_sizes, int n_in,
                              void* d_out, int out_size, void* d_ws, size_t ws_size,
                              hipStream_t stream) {
    const float* F  = (const float*)d_in[0];   // (1024, 680)
    const float* D  = (const float*)d_in[1];   // (48, 24, 48, 680)
    const float* qw = (const float*)d_in[2];   // (24,)
    float* out = (float*)d_out;
    char*  ws  = (char*)d_ws;

    uint4* awt = (uint4*)ws;                                    // 81.0 MiB bf16
    const size_t awt_bytes = (size_t)NCH * DPAD * 64 * 2;       // 84,934,656
    uint2* parts = (uint2*)(ws + awt_bytes);                    // 27.0 MiB bf16
    const size_t parts_bytes = (size_t)SPLITS * NTILE * 16384 * 8;  // 28,311,552
    unsigned short* Mb = (unsigned short*)(ws + awt_bytes + parts_bytes);  // 1.125 MiB
    const size_t mb_bytes = (size_t)DPAD * DPAD * 2;            // 1,179,648
    uint4* Fb = (uint4*)(ws + awt_bytes + parts_bytes + mb_bytes);  // 1.5 MiB

    k1_transpose<<<dim3(NCH / 4, DPAD / 64), 256, 0, stream>>>(D, qw, awt);
    kf_conv<<<dim3(1024 * DPAD / 8 / 256), 256, 0, stream>>>(F, Fb);
    k2_gram<<<dim3(SPLITS * NTILE), 512, 0, stream>>>(awt, parts);
    k2_reduce<<<dim3(32, NTILE), 256, 0, stream>>>(parts, Mb);
    k3_mfma<<<dim3(16, 11), 64, 0, stream>>>(Fb, (const uint4*)Mb, out);
}